// Round 1
// baseline (575.920 us; speedup 1.0000x reference)
//
#include <hip/hip_runtime.h>

typedef __bf16 bf16x8 __attribute__((ext_vector_type(8)));
typedef float f32x4 __attribute__((ext_vector_type(4)));
typedef unsigned int u32x4 __attribute__((ext_vector_type(4)));
typedef unsigned short u16x4 __attribute__((ext_vector_type(4)));

#define S_LEN 2048
#define HDIM  4096
#define KVDIM 1024
#define NHEAD 32
#define NKV   8
#define QKVN  6144   // HDIM + KVDIM + KVDIM
#define GK    4096   // K for both big GEMMs
#define GNT   (GK / 64)

__device__ __forceinline__ unsigned short f2b(float x) {
    unsigned int u = __builtin_bit_cast(unsigned int, x);
    u = (u + 0x7FFFu + ((u >> 16) & 1u)) >> 16;
    return (unsigned short)u;
}
__device__ __forceinline__ float b2f(unsigned short b) {
    unsigned int u = ((unsigned int)b) << 16;
    return __builtin_bit_cast(float, u);
}

// async global->LDS 16B copy (gfx950): LDS dest must be wave-uniform base + lane*16
__device__ __forceinline__ void gl_lds16(const void* g, void* s) {
    __builtin_amdgcn_global_load_lds(
        (const __attribute__((address_space(1))) unsigned int*)g,
        (__attribute__((address_space(3))) unsigned int*)s, 16, 0, 0);
}

__device__ __forceinline__ void sbar() {
    asm volatile("" ::: "memory");
    __builtin_amdgcn_s_barrier();
    asm volatile("" ::: "memory");
    __builtin_amdgcn_sched_barrier(0);  // pin phase structure (MFMA can't cross)
}
#define WAITVM(n) asm volatile("s_waitcnt vmcnt(" #n ")" ::: "memory")

// ---------------- f32 -> bf16 conversion ----------------
__global__ void cvt_kernel(const float* __restrict__ in, unsigned short* __restrict__ out, int n4) {
    int i = blockIdx.x * 256 + threadIdx.x;
    if (i >= n4) return;
    f32x4 v = ((const f32x4*)in)[i];
    u16x4 o;
    o.x = f2b(v.x); o.y = f2b(v.y); o.z = f2b(v.z); o.w = f2b(v.w);
    ((u16x4*)out)[i] = o;
}

// ---------------- 256x256 8-phase NT GEMM: C[M,N] = A[M,K] @ B[N,K]^T ----------------
// 512 threads = 8 waves (WARPS_M=2 x WARPS_N=4), BK=64, 128 KiB LDS.
// LDS per K-tile split into 4 sub-tiles (A-mh0/A-mh1 by row-quarters per wy; B-nh0/B-nh1
// by 32-row stripes per wx), each 16 KiB, each double-buffered by tile parity.
// Phase order (mh0,nh0)->(mh0,nh1)->(mh1,nh1)->(mh1,nh0): one region dies per phase,
// so each phase stages one sub-tile and the K-tile boundary wait is a counted vmcnt(6)
// (3 sub-tiles stay in flight; never drained to 0 in the main loop).
// Swizzle: LDS[row][slot] holds global chunk (slot ^ (row&7)) -- folded into the
// per-lane GLOBAL address; LDS dest stays linear (base + lane*16). Bank-conflict-free.
// MODE 0: C bf16 [M,N]; MODE 1: C f32 [M,N]; MODE 2: QKV split epilogue.
template <int MODE>
__global__ __launch_bounds__(512, 2) void gemm256(const unsigned short* __restrict__ A,
                                                  const unsigned short* __restrict__ B,
                                                  void* __restrict__ C0,
                                                  unsigned short* __restrict__ C1,
                                                  unsigned short* __restrict__ C2,
                                                  int N) {
    __shared__ unsigned short Am[2][2][128][64];  // [mh][parity][lrow][col]
    __shared__ unsigned short Bn[2][2][128][64];  // [nh][parity][lrow][col]

    const int tid = threadIdx.x;
    const int w = tid >> 6, lane = tid & 63;
    const int quad = lane >> 4, l15 = lane & 15;
    const int wy = w >> 2, wx = w & 3;
    const int rsub = lane >> 3, csl = lane & 7;
    const int gch = csl ^ rsub;  // global chunk for staging (XOR swizzle, row&7 == rsub)
    const int m0 = blockIdx.y * 256, n0 = blockIdx.x * 256;

    f32x4 acc[8][4] = {};

    auto stageA = [&](int mh, int par, int kt) {
        if (kt < GNT) {
#pragma unroll
            for (int i = 0; i < 2; ++i) {
                int grow = m0 + i * 128 + mh * 64 + w * 8 + rsub;
                gl_lds16(&A[(size_t)grow * GK + kt * 64 + gch * 8],
                         &Am[mh][par][i * 64 + w * 8 + rsub][csl * 8]);
            }
        }
    };
    auto stageB = [&](int nh, int par, int kt) {
        if (kt < GNT) {
#pragma unroll
            for (int i = 0; i < 2; ++i) {
                int lr = i * 64 + w * 8 + rsub;
                int gn = n0 + (lr >> 5) * 64 + nh * 32 + (lr & 31);
                gl_lds16(&B[(size_t)gn * GK + kt * 64 + gch * 8],
                         &Bn[nh][par][lr][csl * 8]);
            }
        }
    };
    auto rdA = [&](int mh, int par, int mbl, int t) -> bf16x8 {
        return *(const bf16x8*)&Am[mh][par][wy * 64 + mbl * 16 + l15][(((t * 4 + quad) ^ (l15 & 7)) * 8)];
    };
    auto rdB = [&](int nh, int par, int nbl, int t) -> bf16x8 {
        return *(const bf16x8*)&Bn[nh][par][wx * 32 + nbl * 16 + l15][(((t * 4 + quad) ^ (l15 & 7)) * 8)];
    };

    // prologue: tile 0 fully (4 sub-tiles) + tile 1 partially (3 sub-tiles; its B-nh0
    // is staged at phase 1 of tile 0). vmcnt(6) -> tile 0's 8 loads landed.
    stageA(0, 0, 0); stageB(0, 0, 0); stageB(1, 0, 0); stageA(1, 0, 0);
    stageA(0, 1, 1); stageB(1, 1, 1); stageA(1, 1, 1);
    WAITVM(6);
    sbar();

    for (int j = 0; j < GNT; ++j) {
        const int par = j & 1, parn = par ^ 1;
        bf16x8 a[4][2], b[2][2];

        // ---- phase 1: (mh0, nh0). A-mh0 region dies after this phase.
#pragma unroll
        for (int mb = 0; mb < 4; ++mb) { a[mb][0] = rdA(0, par, mb, 0); a[mb][1] = rdA(0, par, mb, 1); }
#pragma unroll
        for (int nb = 0; nb < 2; ++nb) { b[nb][0] = rdB(0, par, nb, 0); b[nb][1] = rdB(0, par, nb, 1); }
        stageB(0, parn, j + 1);
        sbar();
        __builtin_amdgcn_s_setprio(1);
#pragma unroll
        for (int mb = 0; mb < 4; ++mb)
#pragma unroll
            for (int nb = 0; nb < 2; ++nb) {
                acc[mb][nb] = __builtin_amdgcn_mfma_f32_16x16x32_bf16(a[mb][0], b[nb][0], acc[mb][nb], 0, 0, 0);
                acc[mb][nb] = __builtin_amdgcn_mfma_f32_16x16x32_bf16(a[mb][1], b[nb][1], acc[mb][nb], 0, 0, 0);
            }
        __builtin_amdgcn_s_setprio(0);
        sbar();

        // ---- phase 2: (mh0, nh1). B-nh1 region dies after this phase.
#pragma unroll
        for (int nb = 0; nb < 2; ++nb) { b[nb][0] = rdB(1, par, nb, 0); b[nb][1] = rdB(1, par, nb, 1); }
        stageA(0, par, j + 2);  // A-mh0[par] free since end of phase 1
        sbar();
        __builtin_amdgcn_s_setprio(1);
#pragma unroll
        for (int mb = 0; mb < 4; ++mb)
#pragma unroll
            for (int nb = 0; nb < 2; ++nb) {
                acc[mb][nb + 2] = __builtin_amdgcn_mfma_f32_16x16x32_bf16(a[mb][0], b[nb][0], acc[mb][nb + 2], 0, 0, 0);
                acc[mb][nb + 2] = __builtin_amdgcn_mfma_f32_16x16x32_bf16(a[mb][1], b[nb][1], acc[mb][nb + 2], 0, 0, 0);
            }
        __builtin_amdgcn_s_setprio(0);
        sbar();

        // ---- phase 3: (mh1, nh1), reuse b regs. A-mh1 region dies after this phase.
#pragma unroll
        for (int mb = 0; mb < 4; ++mb) { a[mb][0] = rdA(1, par, mb, 0); a[mb][1] = rdA(1, par, mb, 1); }
        stageB(1, par, j + 2);  // B-nh1[par] free since end of phase 2
        sbar();
        __builtin_amdgcn_s_setprio(1);
#pragma unroll
        for (int mb = 0; mb < 4; ++mb)
#pragma unroll
            for (int nb = 0; nb < 2; ++nb) {
                acc[mb + 4][nb + 2] = __builtin_amdgcn_mfma_f32_16x16x32_bf16(a[mb][0], b[nb][0], acc[mb + 4][nb + 2], 0, 0, 0);
                acc[mb + 4][nb + 2] = __builtin_amdgcn_mfma_f32_16x16x32_bf16(a[mb][1], b[nb][1], acc[mb + 4][nb + 2], 0, 0, 0);
            }
        __builtin_amdgcn_s_setprio(0);
        sbar();

        // ---- phase 4: (mh1, nh0), re-read B-nh0. Boundary: counted vmcnt(6).
#pragma unroll
        for (int nb = 0; nb < 2; ++nb) { b[nb][0] = rdB(0, par, nb, 0); b[nb][1] = rdB(0, par, nb, 1); }
        stageA(1, par, j + 2);  // A-mh1[par] free since end of phase 3
        sbar();
        __builtin_amdgcn_s_setprio(1);
#pragma unroll
        for (int mb = 0; mb < 4; ++mb)
#pragma unroll
            for (int nb = 0; nb < 2; ++nb) {
                acc[mb + 4][nb] = __builtin_amdgcn_mfma_f32_16x16x32_bf16(a[mb][0], b[nb][0], acc[mb + 4][nb], 0, 0, 0);
                acc[mb + 4][nb] = __builtin_amdgcn_mfma_f32_16x16x32_bf16(a[mb][1], b[nb][1], acc[mb + 4][nb], 0, 0, 0);
            }
        __builtin_amdgcn_s_setprio(0);
        // tile j+1 fully landed after this wait; tile j+2's 3 staged sub-tiles (6 loads)
        // stay in flight. Epilogue tiles drain to 0.
        if (j + 2 < GNT) { WAITVM(6); } else { WAITVM(0); }
        sbar();
    }

#pragma unroll
    for (int mb = 0; mb < 8; ++mb)
#pragma unroll
        for (int nb = 0; nb < 4; ++nb)
#pragma unroll
            for (int r = 0; r < 4; ++r) {
                int row = m0 + wy * 128 + mb * 16 + quad * 4 + r;
                int gc = n0 + wx * 64 + nb * 16 + l15;
                float v = acc[mb][nb][r];
                if (MODE == 0) {
                    ((unsigned short*)C0)[(size_t)row * N + gc] = f2b(v);
                } else if (MODE == 1) {
                    ((float*)C0)[(size_t)row * N + gc] = v;
                } else {  // QKV split: Q [S,4096] | K [S,1024] | V^T [1024,S]
                    if (gc < HDIM)
                        ((unsigned short*)C0)[(size_t)row * HDIM + gc] = f2b(v);
                    else if (gc < HDIM + KVDIM)
                        C1[(size_t)row * KVDIM + (gc - HDIM)] = f2b(v);
                    else
                        C2[(size_t)(gc - HDIM - KVDIM) * S_LEN + row] = f2b(v);
                }
            }
}

// ---------------- RoPE (in-place, bf16 Q [S,4096] and K [S,1024]) ----------------
__global__ void rope_kernel(unsigned short* __restrict__ Q, unsigned short* __restrict__ Kc,
                            const int* __restrict__ pos_ids) {
    int tid = blockIdx.x * 256 + threadIdx.x;  // S * 40 heads * 64 pairs
    int j = tid & 63;
    int head = (tid >> 6) % (NHEAD + NKV);
    int s = tid / (64 * (NHEAD + NKV));
    float pos = (float)pos_ids[s];
    float inv = exp2f(-(float)j * 0.20762050593046f);  // 10000^(-j/64)
    float ang = pos * inv;
    float sn, cs;
    __sincosf(ang, &sn, &cs);
    unsigned short* p;
    if (head < NHEAD)
        p = Q + (size_t)s * HDIM + head * 128;
    else
        p = Kc + (size_t)s * KVDIM + (head - NHEAD) * 128;
    float x1 = b2f(p[j]), x2 = b2f(p[j + 64]);
    p[j] = f2b(x1 * cs - x2 * sn);
    p[j + 64] = f2b(x2 * cs + x1 * sn);
}

// ---------------- causal GQA flash attention (S^T orientation) ----------------
// Q [S,4096] (post-RoPE), Kb [S,1024] (post-RoPE), Vt [1024,S] (V transposed)
// grid = (NHEAD, S/64), qblk = (S/64-1) - blockIdx.y  => heavy blocks dispatch FIRST
// block = 256 = 4 waves; wave w owns q rows [qblk*64 + w*16, +16)
// S^T = K Q^T so the softmax k-reduction is register-local + 2 shfl (not 16-lane).
__global__ __launch_bounds__(256) void attn_fwd(const unsigned short* __restrict__ Q,
                                                const unsigned short* __restrict__ Kb,
                                                const unsigned short* __restrict__ Vt,
                                                unsigned short* __restrict__ O) {
    __shared__ unsigned short Ks[64][136];   // [kpos][d]
    __shared__ unsigned short Vts[128][72];  // [d][kpos]
    __shared__ unsigned short Ps[4][16][80]; // per-wave P [q_local][kpos], 160B rows

    const int qblk = (gridDim.y - 1) - blockIdx.y;
    const int h = blockIdx.x, kvh = h >> 2;
    const int tid = threadIdx.x, w = tid >> 6, lane = tid & 63;
    const int quad = lane >> 4, l15 = lane & 15;
    const int qg = qblk * 64 + w * 16 + l15;  // this lane's q row (for B-frag & softmax state)

    bf16x8 aq[4];
#pragma unroll
    for (int t = 0; t < 4; ++t)
        aq[t] = *(const bf16x8*)&Q[(size_t)qg * HDIM + h * 128 + t * 32 + quad * 8];

    f32x4 o[8] = {};
    float m_s = -3.0e38f, l_s = 0.f;  // softmax state for q = qg (replicated over quads)
    const float cexp = 0.08838834764831845f * 1.4426950408889634f;  // 1/sqrt(128)*log2(e)

    const int kr0 = tid >> 4, ksg = tid & 15;  // K staging: 16 rows/pass x 16 segs
    const int vr0 = tid >> 3, vsg = tid & 7;   // V staging: 32 rows/pass x 8 segs

    // prefetch tile 0
    u32x4 kpre[4], vpre[4];
#pragma unroll
    for (int p = 0; p < 4; ++p) {
        kpre[p] = *(const u32x4*)&Kb[(size_t)(kr0 + p * 16) * KVDIM + kvh * 128 + ksg * 8];
        vpre[p] = *(const u32x4*)&Vt[(size_t)(kvh * 128 + vr0 + p * 32) * S_LEN + vsg * 8];
    }

    for (int kt = 0; kt <= qblk; ++kt) {
#pragma unroll
        for (int p = 0; p < 4; ++p) {
            *(u32x4*)&Ks[kr0 + p * 16][ksg * 8] = kpre[p];
            *(u32x4*)&Vts[vr0 + p * 32][vsg * 8] = vpre[p];
        }
        __syncthreads();
        if (kt < qblk) {  // prefetch next tile; loads fly while we compute below
            const int k0n = kt * 64 + 64;
#pragma unroll
            for (int p = 0; p < 4; ++p) {
                kpre[p] = *(const u32x4*)&Kb[(size_t)(k0n + kr0 + p * 16) * KVDIM + kvh * 128 + ksg * 8];
                vpre[p] = *(const u32x4*)&Vt[(size_t)(kvh * 128 + vr0 + p * 32) * S_LEN + k0n + vsg * 8];
            }
        }

        // S^T = K Q^T : rows = k (64), cols = q (16/wave)
        f32x4 sc[4] = {};
#pragma unroll
        for (int t = 0; t < 4; ++t)
#pragma unroll
            for (int mb = 0; mb < 4; ++mb) {
                bf16x8 ak = *(const bf16x8*)&Ks[mb * 16 + l15][t * 32 + quad * 8];
                sc[mb] = __builtin_amdgcn_mfma_f32_16x16x32_bf16(ak, aq[t], sc[mb], 0, 0, 0);
            }

        // softmax for q = qg; this lane holds k = mb*16 + quad*4 + r
        float vv[16];
        if (kt == qblk) {  // diagonal tile: causal mask (uniform branch)
#pragma unroll
            for (int mb = 0; mb < 4; ++mb)
#pragma unroll
                for (int r = 0; r < 4; ++r) {
                    int kl = mb * 16 + quad * 4 + r;
                    vv[mb * 4 + r] = (kl <= w * 16 + l15) ? sc[mb][r] * cexp : -3.0e38f;
                }
        } else {
#pragma unroll
            for (int mb = 0; mb < 4; ++mb)
#pragma unroll
                for (int r = 0; r < 4; ++r)
                    vv[mb * 4 + r] = sc[mb][r] * cexp;
        }
        float mx = vv[0];
#pragma unroll
        for (int i = 1; i < 16; ++i) mx = fmaxf(mx, vv[i]);
        mx = fmaxf(mx, __shfl_xor(mx, 16, 64));
        mx = fmaxf(mx, __shfl_xor(mx, 32, 64));
        float mnew = fmaxf(m_s, mx);
        float alpha = exp2f(m_s - mnew);
        m_s = mnew;
        float sum = 0.f;
        unsigned short pb[16];
#pragma unroll
        for (int i = 0; i < 16; ++i) {
            float pp = exp2f(vv[i] - mnew);
            sum += pp;
            pb[i] = f2b(pp);
        }
        sum += __shfl_xor(sum, 16, 64);
        sum += __shfl_xor(sum, 32, 64);
        l_s = l_s * alpha + sum;
        // store P to A-operand home: Ps[w][q_local=l15][k], packed 8B
#pragma unroll
        for (int mb = 0; mb < 4; ++mb) {
            u16x4 pk = {pb[mb * 4 + 0], pb[mb * 4 + 1], pb[mb * 4 + 2], pb[mb * 4 + 3]};
            *(u16x4*)&Ps[w][l15][mb * 16 + quad * 4] = pk;
        }
        // rescale o: row q_local = quad*4 + r needs alpha from lane l15'=quad*4+r (same quad)
        float a4[4];
#pragma unroll
        for (int r = 0; r < 4; ++r) a4[r] = __shfl(alpha, quad * 20 + r, 64);
#pragma unroll
        for (int db = 0; db < 8; ++db)
#pragma unroll
            for (int r = 0; r < 4; ++r) o[db][r] *= a4[r];

        // O += P V
        bf16x8 pa[2];
#pragma unroll
        for (int t = 0; t < 2; ++t)
            pa[t] = *(const bf16x8*)&Ps[w][l15][t * 32 + quad * 8];
#pragma unroll
        for (int db = 0; db < 8; ++db)
#pragma unroll
            for (int t = 0; t < 2; ++t) {
                bf16x8 vb = *(const bf16x8*)&Vts[db * 16 + l15][t * 32 + quad * 8];
                o[db] = __builtin_amdgcn_mfma_f32_16x16x32_bf16(pa[t], vb, o[db], 0, 0, 0);
            }
        __syncthreads();
    }

    float linv[4];
#pragma unroll
    for (int r = 0; r < 4; ++r) linv[r] = 1.0f / __shfl(l_s, quad * 20 + r, 64);
    const int qrow_base = qblk * 64 + w * 16 + quad * 4;
#pragma unroll
    for (int db = 0; db < 8; ++db)
#pragma unroll
        for (int r = 0; r < 4; ++r) {
            int row = qrow_base + r;
            int col = h * 128 + db * 16 + l15;
            O[(size_t)row * HDIM + col] = f2b(o[db][r] * linv[r]);
        }
}

extern "C" void kernel_launch(void* const* d_in, const int* in_sizes, int n_in,
                              void* d_out, int out_size, void* d_ws, size_t ws_size,
                              hipStream_t stream) {
    const float* hid = (const float*)d_in[0];
    const int* pos   = (const int*)d_in[1];
    const float* Wq  = (const float*)d_in[2];
    const float* Wk  = (const float*)d_in[3];
    const float* Wv  = (const float*)d_in[4];
    const float* Wo  = (const float*)d_in[5];
    float* out = (float*)d_out;

    // workspace layout (88 MiB total):
    //   [ 0,16)  hb   : hidden bf16 [S,H]    (reused as attw after QKV gemm consumes it)
    //   [16,64)  Wqkvb: concat Wq|Wk|Wv bf16 [6144,4096]
    //   [16,48)  Wob  : Wo bf16 (ALIASES Wqkvb; converted AFTER the QKV gemm finishes)
    //   [64,80)  Qw   : Q bf16 [S,4096]
    //   [80,84)  Kw   : K bf16 [S,1024]
    //   [84,88)  Vtw  : V^T bf16 [1024,S]
    char* ws = (char*)d_ws;
    unsigned short* hb    = (unsigned short*)(ws);
    unsigned short* Wqkvb = (unsigned short*)(ws + (16ull << 20));
    unsigned short* Wob   = (unsigned short*)(ws + (16ull << 20));
    unsigned short* Qw    = (unsigned short*)(ws + (64ull << 20));
    unsigned short* Kw    = (unsigned short*)(ws + (80ull << 20));
    unsigned short* Vtw   = (unsigned short*)(ws + (84ull << 20));
    unsigned short* attw  = hb;

    // 1. f32 -> bf16 (hidden + Q/K/V weights into concat buffer)
    cvt_kernel<<<(S_LEN * HDIM / 4 + 255) / 256, 256, 0, stream>>>(hid, hb, S_LEN * HDIM / 4);
    cvt_kernel<<<(HDIM * HDIM / 4 + 255) / 256, 256, 0, stream>>>(Wq, Wqkvb, HDIM * HDIM / 4);
    cvt_kernel<<<(KVDIM * HDIM / 4 + 255) / 256, 256, 0, stream>>>(Wk, Wqkvb + (size_t)HDIM * HDIM, KVDIM * HDIM / 4);
    cvt_kernel<<<(KVDIM * HDIM / 4 + 255) / 256, 256, 0, stream>>>(Wv, Wqkvb + (size_t)(HDIM + KVDIM) * HDIM, KVDIM * HDIM / 4);

    // 2. fused QKV projection: C [2048,6144] routed to Qw | Kw | Vtw
    gemm256<2><<<dim3(QKVN / 256, S_LEN / 256), 512, 0, stream>>>(hb, Wqkvb, Qw, Kw, Vtw, QKVN);

    // 3. Wo conversion (into region aliasing the now-dead QKV weights)
    cvt_kernel<<<(HDIM * HDIM / 4 + 255) / 256, 256, 0, stream>>>(Wo, Wob, HDIM * HDIM / 4);

    // 4. RoPE on Q,K
    rope_kernel<<<S_LEN * (NHEAD + NKV) * 64 / 256, 256, 0, stream>>>(Qw, Kw, pos);

    // 5. causal GQA attention (heavy-first dispatch)
    attn_fwd<<<dim3(NHEAD, S_LEN / 64), 256, 0, stream>>>(Qw, Kw, Vtw, attw);

    // 6. output projection -> f32
    gemm256<1><<<dim3(HDIM / 256, S_LEN / 256), 512, 0, stream>>>(attw, Wob, out, nullptr, nullptr, HDIM);
}

// Round 2
// 485.428 us; speedup vs baseline: 1.1864x; 1.1864x over previous
//
#include <hip/hip_runtime.h>

typedef __bf16 bf16x8 __attribute__((ext_vector_type(8)));
typedef float f32x4 __attribute__((ext_vector_type(4)));
typedef unsigned int u32x4 __attribute__((ext_vector_type(4)));
typedef unsigned short u16x4 __attribute__((ext_vector_type(4)));

#define S_LEN 2048
#define HDIM  4096
#define KVDIM 1024
#define NHEAD 32
#define NKV   8
#define QKVN  6144

__device__ __forceinline__ unsigned short f2b(float x) {
    unsigned int u = __builtin_bit_cast(unsigned int, x);
    u = (u + 0x7FFFu + ((u >> 16) & 1u)) >> 16;
    return (unsigned short)u;
}
__device__ __forceinline__ float b2f(unsigned short b) {
    unsigned int u = ((unsigned int)b) << 16;
    return __builtin_bit_cast(float, u);
}

// async global->LDS 16B copy (gfx950): LDS dest must be wave-uniform base + lane*16
__device__ __forceinline__ void gl_lds16(const void* g, void* s) {
    __builtin_amdgcn_global_load_lds(
        (const __attribute__((address_space(1))) unsigned int*)g,
        (__attribute__((address_space(3))) unsigned int*)s, 16, 0, 0);
}

// ---------------- fused f32 -> bf16 conversion (hidden + Wq|Wk|Wv concat) ----------------
__global__ void cvt_all(const float* __restrict__ hid, const float* __restrict__ Wq,
                        const float* __restrict__ Wk, const float* __restrict__ Wv,
                        unsigned short* __restrict__ hb, unsigned short* __restrict__ Wqkvb) {
    const int NH = S_LEN * HDIM / 4;   // 2097152
    const int NQ = HDIM * HDIM / 4;    // 4194304
    const int NK = KVDIM * HDIM / 4;   // 1048576
    int i = blockIdx.x * 256 + threadIdx.x;  // total NH+NQ+2*NK = 8388608
    const float* src;
    unsigned short* dst;
    int off;
    if (i < NH) { src = hid; dst = hb; off = i; }
    else if (i < NH + NQ) { src = Wq; dst = Wqkvb; off = i - NH; }
    else if (i < NH + NQ + NK) { src = Wk; dst = Wqkvb + (size_t)HDIM * HDIM; off = i - NH - NQ; }
    else { src = Wv; dst = Wqkvb + (size_t)(HDIM + KVDIM) * HDIM; off = i - NH - NQ - NK; }
    f32x4 v = ((const f32x4*)src)[off];
    u16x4 o;
    o.x = f2b(v.x); o.y = f2b(v.y); o.z = f2b(v.z); o.w = f2b(v.w);
    ((u16x4*)dst)[off] = o;
}

// ---------------- plain f32 -> bf16 conversion (Wo, after QKV gemm frees its alias) ----------------
__global__ void cvt_kernel(const float* __restrict__ in, unsigned short* __restrict__ out, int n4) {
    int i = blockIdx.x * 256 + threadIdx.x;
    if (i >= n4) return;
    f32x4 v = ((const f32x4*)in)[i];
    u16x4 o;
    o.x = f2b(v.x); o.y = f2b(v.y); o.z = f2b(v.z); o.w = f2b(v.w);
    ((u16x4*)out)[i] = o;
}

// ---------------- NT GEMM body: C[M,N] = A[M,K] @ B[N,K]^T (m97 structure) ----------------
// global_load_lds width-16 staging into UNPADDED LDS tiles with XOR-chunk swizzle folded
// into the GLOBAL address (LDS dest stays base+lane*16).
// MODE 0: C bf16 [M,N]; MODE 1: C bf16 transposed [N,M]; MODE 2: C f32 [M,N]
// n0 indexes B rows (global); cn0 indexes C columns (local to the C buffer).
template <int MODE>
__device__ __forceinline__ void gemm_body(const unsigned short* __restrict__ A,
                                          const unsigned short* __restrict__ B,
                                          void* __restrict__ Cv,
                                          int M, int N, int K, int m0, int n0, int cn0,
                                          unsigned short (*As)[64], unsigned short (*Bs)[64]) {
    const int tid = threadIdx.x;
    const int w = tid >> 6, lane = tid & 63, quad = lane >> 4, l15 = lane & 15;
    const int wy = w >> 1, wx = w & 1;
    // staging: each wave covers 8 rows/pass, 4 passes -> 32 rows; 4 waves -> 128 rows
    const int srowb = w * 32 + (lane >> 3);          // + p*8
    const int gchunk = (lane & 7) ^ (lane >> 3);     // XOR swizzle (r&7 == lane>>3)
    const int lcol = (lane & 7) * 8;                 // LDS slot col (elements)

    f32x4 acc[4][4] = {};

    for (int k0 = 0; k0 < K; k0 += 64) {
#pragma unroll
        for (int p = 0; p < 4; ++p) {
            int r = srowb + p * 8;
            gl_lds16(&A[(size_t)(m0 + r) * K + k0 + gchunk * 8], &As[r][lcol]);
            gl_lds16(&B[(size_t)(n0 + r) * K + k0 + gchunk * 8], &Bs[r][lcol]);
        }
        __syncthreads();
#pragma unroll
        for (int t = 0; t < 2; ++t) {
            bf16x8 af[4], bfr[4];
#pragma unroll
            for (int mb = 0; mb < 4; ++mb)
                af[mb] = *(const bf16x8*)&As[wy * 64 + mb * 16 + l15][(((t * 4 + quad) ^ (l15 & 7)) * 8)];
#pragma unroll
            for (int nb = 0; nb < 4; ++nb)
                bfr[nb] = *(const bf16x8*)&Bs[wx * 64 + nb * 16 + l15][(((t * 4 + quad) ^ (l15 & 7)) * 8)];
#pragma unroll
            for (int mb = 0; mb < 4; ++mb)
#pragma unroll
                for (int nb = 0; nb < 4; ++nb)
                    acc[mb][nb] = __builtin_amdgcn_mfma_f32_16x16x32_bf16(af[mb], bfr[nb], acc[mb][nb], 0, 0, 0);
        }
        __syncthreads();
    }
#pragma unroll
    for (int mb = 0; mb < 4; ++mb)
#pragma unroll
        for (int nb = 0; nb < 4; ++nb)
#pragma unroll
            for (int r = 0; r < 4; ++r) {
                int row = m0 + wy * 64 + mb * 16 + quad * 4 + r;
                int col = cn0 + wx * 64 + nb * 16 + l15;
                float v = acc[mb][nb][r];
                if (MODE == 0)
                    ((unsigned short*)Cv)[(size_t)row * N + col] = f2b(v);
                else if (MODE == 1)
                    ((unsigned short*)Cv)[(size_t)col * M + row] = f2b(v);
                else
                    ((float*)Cv)[(size_t)row * N + col] = v;
            }
}

template <int MODE>
__global__ __launch_bounds__(256) void gemm_nt(const unsigned short* __restrict__ A,
                                               const unsigned short* __restrict__ B,
                                               void* __restrict__ Cv, int M, int N, int K) {
    __shared__ unsigned short As[128][64];
    __shared__ unsigned short Bs[128][64];
    gemm_body<MODE>(A, B, Cv, M, N, K, blockIdx.y * 128, blockIdx.x * 128, blockIdx.x * 128, As, Bs);
}

// fused QKV projection against concat weight [6144,4096]: grid (48, 16)
//   bx  0..31 -> Q  bf16 [S,4096]
//   bx 32..39 -> K  bf16 [S,1024]
//   bx 40..47 -> V^T bf16 [1024,S]
__global__ __launch_bounds__(256) void gemm_qkv(const unsigned short* __restrict__ A,
                                                const unsigned short* __restrict__ W,
                                                unsigned short* __restrict__ Q,
                                                unsigned short* __restrict__ Kc,
                                                unsigned short* __restrict__ Vt,
                                                int M, int K) {
    __shared__ unsigned short As[128][64];
    __shared__ unsigned short Bs[128][64];
    const int bx = blockIdx.x, m0 = blockIdx.y * 128, n0 = bx * 128;
    if (bx < 32)
        gemm_body<0>(A, W, Q, M, HDIM, K, m0, n0, n0, As, Bs);
    else if (bx < 40)
        gemm_body<0>(A, W, Kc, M, KVDIM, K, m0, n0, n0 - HDIM, As, Bs);
    else
        gemm_body<1>(A, W, Vt, M, KVDIM, K, m0, n0, n0 - HDIM - KVDIM, As, Bs);
}

// ---------------- RoPE (in-place, bf16 Q [S,4096] and K [S,1024]) ----------------
__global__ void rope_kernel(unsigned short* __restrict__ Q, unsigned short* __restrict__ Kc,
                            const int* __restrict__ pos_ids) {
    int tid = blockIdx.x * 256 + threadIdx.x;  // S * 40 heads * 64 pairs
    int j = tid & 63;
    int head = (tid >> 6) % (NHEAD + NKV);
    int s = tid / (64 * (NHEAD + NKV));
    float pos = (float)pos_ids[s];
    float inv = exp2f(-(float)j * 0.20762050593046f);  // 10000^(-j/64)
    float ang = pos * inv;
    float sn, cs;
    __sincosf(ang, &sn, &cs);
    unsigned short* p;
    if (head < NHEAD)
        p = Q + (size_t)s * HDIM + head * 128;
    else
        p = Kc + (size_t)s * KVDIM + (head - NHEAD) * 128;
    float x1 = b2f(p[j]), x2 = b2f(p[j + 64]);
    p[j] = f2b(x1 * cs - x2 * sn);
    p[j + 64] = f2b(x2 * cs + x1 * sn);
}

// ---------------- causal GQA flash attention (S^T orientation) ----------------
// Q [S,4096] (post-RoPE), Kb [S,1024] (post-RoPE), Vt [1024,S] (V transposed)
// grid = (NHEAD, S/64), qblk = (S/64-1) - blockIdx.y  => heavy blocks dispatch FIRST
// block = 256 = 4 waves; wave w owns q rows [qblk*64 + w*16, +16)
// S^T = K Q^T so the softmax k-reduction is register-local + 2 shfl (not 16-lane).
// T13 defer-max (THR=8 base-2), T5 setprio around MFMA, hw bf16 cvt for P-pack.
__global__ __launch_bounds__(256) void attn_fwd(const unsigned short* __restrict__ Q,
                                                const unsigned short* __restrict__ Kb,
                                                const unsigned short* __restrict__ Vt,
                                                unsigned short* __restrict__ O) {
    __shared__ unsigned short Ks[64][136];   // [kpos][d]
    __shared__ unsigned short Vts[128][72];  // [d][kpos]
    __shared__ unsigned short Ps[4][16][88]; // per-wave P [q_local][kpos]; 176B rows (16B-aligned, 2-way banks)

    const int qblk = (gridDim.y - 1) - blockIdx.y;
    const int h = blockIdx.x, kvh = h >> 2;
    const int tid = threadIdx.x, w = tid >> 6, lane = tid & 63;
    const int quad = lane >> 4, l15 = lane & 15;
    const int qg = qblk * 64 + w * 16 + l15;  // this lane's q row (for B-frag & softmax state)

    bf16x8 aq[4];
#pragma unroll
    for (int t = 0; t < 4; ++t)
        aq[t] = *(const bf16x8*)&Q[(size_t)qg * HDIM + h * 128 + t * 32 + quad * 8];

    f32x4 o[8] = {};
    float m_s = -3.0e38f, l_s = 0.f;  // softmax state for q = qg (replicated over quads)
    const float cexp = 0.08838834764831845f * 1.4426950408889634f;  // 1/sqrt(128)*log2(e)

    const int kr0 = tid >> 4, ksg = tid & 15;  // K staging: 16 rows/pass x 16 segs
    const int vr0 = tid >> 3, vsg = tid & 7;   // V staging: 32 rows/pass x 8 segs

    // prefetch tile 0
    u32x4 kpre[4], vpre[4];
#pragma unroll
    for (int p = 0; p < 4; ++p) {
        kpre[p] = *(const u32x4*)&Kb[(size_t)(kr0 + p * 16) * KVDIM + kvh * 128 + ksg * 8];
        vpre[p] = *(const u32x4*)&Vt[(size_t)(kvh * 128 + vr0 + p * 32) * S_LEN + vsg * 8];
    }

    for (int kt = 0; kt <= qblk; ++kt) {
#pragma unroll
        for (int p = 0; p < 4; ++p) {
            *(u32x4*)&Ks[kr0 + p * 16][ksg * 8] = kpre[p];
            *(u32x4*)&Vts[vr0 + p * 32][vsg * 8] = vpre[p];
        }
        __syncthreads();
        if (kt < qblk) {  // prefetch next tile; loads fly while we compute below
            const int k0n = kt * 64 + 64;
#pragma unroll
            for (int p = 0; p < 4; ++p) {
                kpre[p] = *(const u32x4*)&Kb[(size_t)(k0n + kr0 + p * 16) * KVDIM + kvh * 128 + ksg * 8];
                vpre[p] = *(const u32x4*)&Vt[(size_t)(kvh * 128 + vr0 + p * 32) * S_LEN + k0n + vsg * 8];
            }
        }

        // S^T = K Q^T : rows = k (64), cols = q (16/wave)
        f32x4 sc[4] = {};
        __builtin_amdgcn_s_setprio(1);
#pragma unroll
        for (int t = 0; t < 4; ++t)
#pragma unroll
            for (int mb = 0; mb < 4; ++mb) {
                bf16x8 ak = *(const bf16x8*)&Ks[mb * 16 + l15][t * 32 + quad * 8];
                sc[mb] = __builtin_amdgcn_mfma_f32_16x16x32_bf16(ak, aq[t], sc[mb], 0, 0, 0);
            }
        __builtin_amdgcn_s_setprio(0);

        // softmax for q = qg; this lane holds k = mb*16 + quad*4 + r
        float vv[16];
        if (kt == qblk) {  // diagonal tile: causal mask (uniform branch)
#pragma unroll
            for (int mb = 0; mb < 4; ++mb)
#pragma unroll
                for (int r = 0; r < 4; ++r) {
                    int kl = mb * 4 ? 0 : 0, _ = kl;  // (placeholder removed below)
                    int kk = mb * 16 + quad * 4 + r;
                    vv[mb * 4 + r] = (kk <= w * 16 + l15) ? sc[mb][r] * cexp : -3.0e38f;
                }
        } else {
#pragma unroll
            for (int mb = 0; mb < 4; ++mb)
#pragma unroll
                for (int r = 0; r < 4; ++r)
                    vv[mb * 4 + r] = sc[mb][r] * cexp;
        }
        // tree max (depth 4)
        float m8[8];
#pragma unroll
        for (int i = 0; i < 8; ++i) m8[i] = fmaxf(vv[i], vv[i + 8]);
        float mx = fmaxf(fmaxf(fmaxf(m8[0], m8[1]), fmaxf(m8[2], m8[3])),
                         fmaxf(fmaxf(m8[4], m8[5]), fmaxf(m8[6], m8[7])));
        mx = fmaxf(mx, __shfl_xor(mx, 16, 64));
        mx = fmaxf(mx, __shfl_xor(mx, 32, 64));
        // T13 defer-max: skip rescale when growth bounded (P then bounded by 2^8; bf16/f32 tolerate)
        if (!__all(mx - m_s <= 8.0f)) {
            float mnew = fmaxf(m_s, mx);
            float alpha = exp2f(m_s - mnew);
            m_s = mnew;
            l_s *= alpha;
            // rescale o: row q_local = quad*4 + r needs alpha from lane l15'=quad*4+r (same quad)
            float a4[4];
#pragma unroll
            for (int r = 0; r < 4; ++r) a4[r] = __shfl(alpha, quad * 20 + r, 64);
#pragma unroll
            for (int db = 0; db < 8; ++db)
#pragma unroll
                for (int r = 0; r < 4; ++r) o[db][r] *= a4[r];
        }
        float sum = 0.f;
        __bf16 pb[16] __attribute__((aligned(8)));
#pragma unroll
        for (int i = 0; i < 16; ++i) {
            float pp = exp2f(vv[i] - m_s);
            sum += pp;
            pb[i] = (__bf16)pp;  // hw RTNE cvt (pairs -> v_cvt_pk_bf16_f32)
        }
        sum += __shfl_xor(sum, 16, 64);
        sum += __shfl_xor(sum, 32, 64);
        l_s += sum;
        // store P to A-operand home: Ps[w][q_local=l15][k], packed 8B
#pragma unroll
        for (int mb = 0; mb < 4; ++mb)
            *(u16x4*)&Ps[w][l15][mb * 16 + quad * 4] = *(const u16x4*)&pb[mb * 4];

        // O += P V
        bf16x8 pa[2];
#pragma unroll
        for (int t = 0; t < 2; ++t)
            pa[t] = *(const bf16x8*)&Ps[w][l15][t * 32 + quad * 8];
        __builtin_amdgcn_s_setprio(1);
#pragma unroll
        for (int db = 0; db < 8; ++db)
#pragma unroll
            for (int t = 0; t < 2; ++t) {
                bf16x8 vb = *(const bf16x8*)&Vts[db * 16 + l15][t * 32 + quad * 8];
                o[db] = __builtin_amdgcn_mfma_f32_16x16x32_bf16(pa[t], vb, o[db], 0, 0, 0);
            }
        __builtin_amdgcn_s_setprio(0);
        __syncthreads();
    }

    float linv[4];
#pragma unroll
    for (int r = 0; r < 4; ++r) linv[r] = 1.0f / __shfl(l_s, quad * 20 + r, 64);
    const int qrow_base = qblk * 64 + w * 16 + quad * 4;
#pragma unroll
    for (int db = 0; db < 8; ++db)
#pragma unroll
        for (int r = 0; r < 4; ++r) {
            int row = qrow_base + r;
            int col = h * 128 + db * 16 + l15;
            O[(size_t)row * HDIM + col] = f2b(o[db][r] * linv[r]);
        }
}

extern "C" void kernel_launch(void* const* d_in, const int* in_sizes, int n_in,
                              void* d_out, int out_size, void* d_ws, size_t ws_size,
                              hipStream_t stream) {
    const float* hid = (const float*)d_in[0];
    const int* pos   = (const int*)d_in[1];
    const float* Wq  = (const float*)d_in[2];
    const float* Wk  = (const float*)d_in[3];
    const float* Wv  = (const float*)d_in[4];
    const float* Wo  = (const float*)d_in[5];
    float* out = (float*)d_out;

    // workspace layout (88 MiB total):
    //   [ 0,16)  hb   : hidden bf16 [S,H]    (reused as attw after QKV gemm consumes it)
    //   [16,64)  Wqkvb: concat Wq|Wk|Wv bf16 [6144,4096]
    //   [16,48)  Wob  : Wo bf16 (ALIASES Wqkvb; converted AFTER the QKV gemm finishes)
    //   [64,80)  Qw   : Q bf16 [S,4096]
    //   [80,84)  Kw   : K bf16 [S,1024]
    //   [84,88)  Vtw  : V^T bf16 [1024,S]
    char* ws = (char*)d_ws;
    unsigned short* hb    = (unsigned short*)(ws);
    unsigned short* Wqkvb = (unsigned short*)(ws + (16ull << 20));
    unsigned short* Wob   = (unsigned short*)(ws + (16ull << 20));
    unsigned short* Qw    = (unsigned short*)(ws + (64ull << 20));
    unsigned short* Kw    = (unsigned short*)(ws + (80ull << 20));
    unsigned short* Vtw   = (unsigned short*)(ws + (84ull << 20));
    unsigned short* attw  = hb;

    // 1. one fused f32->bf16 pass: hidden -> hb, Wq|Wk|Wv -> Wqkvb
    cvt_all<<<(S_LEN * HDIM / 4 + HDIM * HDIM / 4 + 2 * (KVDIM * HDIM / 4)) / 256, 256, 0, stream>>>(
        hid, Wq, Wk, Wv, hb, Wqkvb);

    // 2. fused QKV projection: one launch, 768 blocks (3 blocks/CU)
    gemm_qkv<<<dim3(QKVN / 128, S_LEN / 128), 256, 0, stream>>>(hb, Wqkvb, Qw, Kw, Vtw, S_LEN, HDIM);

    // 3. Wo conversion (into region aliasing the now-dead QKV weights)
    cvt_kernel<<<(HDIM * HDIM / 4 + 255) / 256, 256, 0, stream>>>(Wo, Wob, HDIM * HDIM / 4);

    // 4. RoPE on Q,K
    rope_kernel<<<S_LEN * (NHEAD + NKV) * 64 / 256, 256, 0, stream>>>(Qw, Kw, pos);

    // 5. causal GQA attention (heavy-first dispatch)
    attn_fwd<<<dim3(NHEAD, S_LEN / 64), 256, 0, stream>>>(Qw, Kw, Vtw, attw);

    // 6. output projection -> f32
    gemm_nt<2><<<dim3(HDIM / 128, S_LEN / 128), 256, 0, stream>>>(attw, Wob, out, S_LEN, HDIM, HDIM);
}